// Round 13
// baseline (2389.842 us; speedup 1.0000x reference)
//
#include <hip/hip_runtime.h>
#include <cstdint>
#include <cstddef>

#define HID 3000
#define HP  3072          // padded hidden (2^10 * 3)
#define NB  1024          // batch
#define BM  128           // mlp3 tile
#define BN  64            // mlp3 per-tile N
#define KT  48            // HP/64 K-steps for gru
#define BUFSZ 51200       // gru LDS buffer: A 256x64 f16 (32KB) + B 144x64 f16 (18KB)
#define PLANE 13312       // 256*52 f32 per gate plane (epilogue)

typedef _Float16 f16;
typedef _Float16 f16x8 __attribute__((ext_vector_type(8)));
typedef float    f32x4 __attribute__((ext_vector_type(4)));

__device__ __forceinline__ float sigf(float v)  { return 1.0f / (1.0f + __expf(-v)); }
__device__ __forceinline__ float tanhf_(float v){ return 2.0f / (1.0f + __expf(-2.0f * v)) - 1.0f; }

// async global->LDS, 16B per lane. LDS dest = wave-uniform base + lane*16 (linear).
__device__ __forceinline__ void gload16(const void* g, void* l) {
    __builtin_amdgcn_global_load_lds((const __attribute__((address_space(1))) void*)g,
                                     (__attribute__((address_space(3))) void*)l, 16, 0, 0);
}

// ---------------- Whh fp32 -> fp16, padded [3][HP][HP]; 128B-in/64B-out per thread
__global__ __launch_bounds__(256) void convert_whh(const float* __restrict__ whh,
                                                   f16* __restrict__ whh16)
{
    const int S32 = 3 * HP * (HP / 32);
    int t = blockIdx.x * 256 + threadIdx.x;
    if (t >= S32) return;
    const int c32 = (t % (HP / 32)) * 32;
    const int rr  = (t / (HP / 32)) % HP;
    const int g   = t / ((HP / 32) * HP);
    f16* dst = whh16 + ((size_t)g * HP + rr) * HP + c32;
    if (rr < HID && c32 + 32 <= HID) {
        const float* src = whh + (size_t)(g * HID + rr) * HID + c32;
#pragma unroll
        for (int u = 0; u < 4; ++u) {
            float4 lo = *reinterpret_cast<const float4*>(src + u * 8);
            float4 hi = *reinterpret_cast<const float4*>(src + u * 8 + 4);
            f16x8 v;
            v[0] = (f16)lo.x; v[1] = (f16)lo.y; v[2] = (f16)lo.z; v[3] = (f16)lo.w;
            v[4] = (f16)hi.x; v[5] = (f16)hi.y; v[6] = (f16)hi.z; v[7] = (f16)hi.w;
            *reinterpret_cast<f16x8*>(dst + u * 8) = v;
        }
    } else {
#pragma unroll
        for (int u = 0; u < 4; ++u) {
            f16x8 v;
#pragma unroll
            for (int k = 0; k < 8; ++k) {
                const int cc = c32 + u * 8 + k;
                v[k] = (rr < HID && cc < HID) ? (f16)whh[(size_t)(g * HID + rr) * HID + cc]
                                              : (f16)0.0f;
            }
            *reinterpret_cast<f16x8*>(dst + u * 8) = v;
        }
    }
}

// ---------------- W3 fp32 [3000][256] -> f16 [HP][256], zero-padded rows
__global__ __launch_bounds__(256) void convert_w3(const float* __restrict__ w,
                                                  f16* __restrict__ w16)
{
    int t = blockIdx.x * 256 + threadIdx.x;      // HP * 32 slots of 8
    if (t >= HP * 32) return;
    int rr = t >> 5, c8 = (t & 31) * 8;
    f16x8 v;
    if (rr < HID) {
        const float* src = w + (size_t)rr * 256 + c8;
        float4 lo = *reinterpret_cast<const float4*>(src);
        float4 hi = *reinterpret_cast<const float4*>(src + 4);
        v[0] = (f16)lo.x; v[1] = (f16)lo.y; v[2] = (f16)lo.z; v[3] = (f16)lo.w;
        v[4] = (f16)hi.x; v[5] = (f16)hi.y; v[6] = (f16)hi.z; v[7] = (f16)hi.w;
    } else {
#pragma unroll
        for (int i = 0; i < 8; ++i) v[i] = (f16)0.0f;
    }
    *reinterpret_cast<f16x8*>(w16 + (size_t)rr * 256 + c8) = v;
}

// ---------------- gate-parameter pack: [HID][16] f32 = w0[3], w1[3], w2[3],
// bi0 (=bih+bhh), bi1 (=bih+bhh), bi2 (=bih), bh2 (=bhh), pad[3]
__global__ __launch_bounds__(256) void pack_gates(const float* __restrict__ Wih,
                                                  const float* __restrict__ bih,
                                                  const float* __restrict__ bhh,
                                                  float* __restrict__ pk)
{
    int j = blockIdx.x * 256 + threadIdx.x;
    if (j >= HID) return;
    float* o = pk + (size_t)j * 16;
#pragma unroll
    for (int g = 0; g < 3; ++g) {
        const float* w = Wih + (size_t)(g * HID + j) * 3;
        o[g * 3 + 0] = w[0]; o[g * 3 + 1] = w[1]; o[g * 3 + 2] = w[2];
    }
    o[9]  = bih[j] + bhh[j];
    o[10] = bih[HID + j] + bhh[HID + j];
    o[11] = bih[2 * HID + j];
    o[12] = bhh[2 * HID + j];
    o[13] = 0.f; o[14] = 0.f; o[15] = 0.f;
}

// ---------------- small fp32 MLP layer: out = relu(A @ W^T + b), optional f16 copy
__global__ __launch_bounds__(256) void mlp_layer(const float* __restrict__ A, int K, int N, int ldo,
                                                 const float* __restrict__ W,
                                                 const float* __restrict__ bias,
                                                 float* __restrict__ outf, f16* __restrict__ outh)
{
    __shared__ float sA[4 * 512];
    const int b0 = blockIdx.x * 4;
    for (int idx = threadIdx.x; idx < 4 * K; idx += 256)
        sA[idx] = A[(size_t)b0 * K + idx];
    __syncthreads();
    for (int n = threadIdx.x; n < ldo; n += 256) {
        float acc[4] = {0.f, 0.f, 0.f, 0.f};
        if (n < N) {
            const float4* wr = reinterpret_cast<const float4*>(W + (size_t)n * K);
            for (int kk = 0; kk < (K >> 2); ++kk) {
                float4 w = wr[kk];
#pragma unroll
                for (int r = 0; r < 4; ++r) {
                    const float* ar = sA + r * K + kk * 4;
                    acc[r] += ar[0] * w.x + ar[1] * w.y + ar[2] * w.z + ar[3] * w.w;
                }
            }
            float bv = bias[n];
#pragma unroll
            for (int r = 0; r < 4; ++r) acc[r] = fmaxf(acc[r] + bv, 0.f);
        }
#pragma unroll
        for (int r = 0; r < 4; ++r) {
            if (outf) outf[(size_t)(b0 + r) * ldo + n] = acc[r];
            if (outh) outh[(size_t)(b0 + r) * ldo + n] = (f16)acc[r];
        }
    }
}

// ---------------- W3 layer via MFMA: h16 = relu(A @ B^T + b3); A [NB][256] f16, B [HP][256] f16
__global__ __launch_bounds__(256, 2)
void mlp3_mfma(const f16* __restrict__ A, const f16* __restrict__ B,
               const float* __restrict__ bias,
               f16* __restrict__ outh)
{
    __shared__ __align__(16) char smem[24576];   // sA 16KB | sB 8KB
    char* sBm = smem + 16384;

    const int tid  = threadIdx.x;
    const int lane = tid & 63;
    const int wid  = tid >> 6;
    const int wm = wid >> 1, wn = wid & 1;
    const int l15 = lane & 15, lhi = lane >> 4;
    const int swz = (lane & 7) << 4;

    const int gm0 = blockIdx.y * BM, gn0 = blockIdx.x * BN;

    const f16* a_srcs[4]; char* a_ldst[4];
#pragma unroll
    for (int i = 0; i < 4; ++i) {
        const int d = (i * 4 + wid) * 64 + lane;          // [0,1024)
        const int r = d >> 3;
        const int c = (d & 7) ^ (r & 7);
        a_srcs[i] = A + (size_t)(gm0 + r) * 256 + c * 8;
        a_ldst[i] = smem + (i * 4 + wid) * 1024;
    }
    const f16* b_srcs[2]; char* b_ldst[2];
#pragma unroll
    for (int i = 0; i < 2; ++i) {
        const int d = (i * 4 + wid) * 64 + lane;          // [0,512)
        const int rr = d >> 3;
        const int c = (d & 7) ^ (rr & 7);
        b_srcs[i] = B + (size_t)(gn0 + rr) * 256 + c * 8;
        b_ldst[i] = sBm + (i * 4 + wid) * 1024;
    }

    f32x4 acc[4][2];
#pragma unroll
    for (int m = 0; m < 4; ++m)
#pragma unroll
        for (int n = 0; n < 2; ++n) acc[m][n] = (f32x4){0.f, 0.f, 0.f, 0.f};

    for (int kt = 0; kt < 4; ++kt) {
        const int kg = kt * 64;
#pragma unroll
        for (int i = 0; i < 4; ++i) gload16(a_srcs[i] + kg, a_ldst[i]);
#pragma unroll
        for (int i = 0; i < 2; ++i) gload16(b_srcs[i] + kg, b_ldst[i]);
        __syncthreads();
#pragma unroll
        for (int kk = 0; kk < 2; ++kk) {
            const int ko = (kk * 64 + lhi * 16) ^ swz;
            f16x8 af[4], bf[2];
#pragma unroll
            for (int m = 0; m < 4; ++m)
                af[m] = *reinterpret_cast<const f16x8*>(smem + (wm * 64 + m * 16 + l15) * 128 + ko);
#pragma unroll
            for (int n = 0; n < 2; ++n)
                bf[n] = *reinterpret_cast<const f16x8*>(sBm + (wn * 32 + n * 16 + l15) * 128 + ko);
#pragma unroll
            for (int m = 0; m < 4; ++m)
#pragma unroll
                for (int n = 0; n < 2; ++n)
                    acc[m][n] = __builtin_amdgcn_mfma_f32_16x16x32_f16(af[m], bf[n], acc[m][n], 0, 0, 0);
        }
        __syncthreads();
    }

#pragma unroll
    for (int m = 0; m < 4; ++m) {
#pragma unroll
        for (int e = 0; e < 4; ++e) {
            const int b = gm0 + wm * 64 + m * 16 + lhi * 4 + e;
#pragma unroll
            for (int n = 0; n < 2; ++n) {
                const int j = gn0 + wn * 32 + n * 16 + l15;
                if (j < HID) {
                    float v = fmaxf(acc[m][n][e] + bias[j], 0.f);
                    outh[(size_t)b * HP + j] = (f16)v;
                }
            }
        }
    }
}

// ---------------- fused GRU step (R12 structure, f16-state + packed-gate epilogue):
// 256x144 tile, 12 waves (4M x 3N=gate), grid 256 = 1/CU. Triple-buffered LDS, depth-2
// prefetch, ONE barrier + counted vmcnt per K-step; hoisted 14 ds_read -> STAGE ->
// 24-MFMA setprio cluster. LDS-plane gate exchange epilogue; state carried in f16 only.
__global__ __launch_bounds__(768, 3)
void gru_step(const f16* __restrict__ h16c,
              const f16* __restrict__ whh16,
              const float* __restrict__ xprev,
              const float* __restrict__ pk,
              f16* __restrict__ h16n)
{
    __shared__ __align__(16) char smem[159744];  // 3 x 51200 bufs; reused as 3 x 53248 planes

    const int tid  = threadIdx.x;
    const int lane = tid & 63;
    const int wid  = tid >> 6;          // 0..11
    const int wm   = wid & 3;           // row group: rows [wm*64, wm*64+64)
    const int wn   = wid >> 2;          // gate 0..2
    const int l15 = lane & 15, lhi = lane >> 4;
    const int swz = (lane & 7) << 4;

    // XCD-bijective: xcd owns bn in [8*xcd, 8*xcd+8); the 4 bm-blocks of a bn share one XCD.
    const int id = blockIdx.x;
    const int xcd = id & 7, local = id >> 3;
    const int bn = xcd * 8 + (local >> 2), bm = local & 3;
    const int gm0 = bm * 256, gn0 = bn * 48;

    // staging: slots of 16B. A: 0..2047 (256 rows x 8), B: 2048..3199 (144 rows x 8).
    // LDS dest linear (slot*16); inverse XOR-swizzle applied to the GLOBAL source column.
    const f16* srcs[5];
#pragma unroll
    for (int i = 0; i < 4; ++i) {
        const int s = i * 768 + tid;
        if (s < 2048) {
            const int r = s >> 3;
            const int c = (s & 7) ^ (r & 7);
            srcs[i] = h16c + (size_t)(gm0 + r) * HP + c * 8;
        } else {
            const int sb = s - 2048;
            const int rr = sb >> 3;                  // g*48 + j'
            const int g = rr / 48, jj = rr - g * 48;
            const int c = (sb & 7) ^ (rr & 7);
            srcs[i] = whh16 + (size_t)g * HP * HP + (size_t)(gn0 + jj) * HP + c * 8;
        }
    }
    {
        const int sb = 1024 + tid;                   // used only when tid < 128
        const int rr = sb >> 3;                      // 128..143 -> gate 2
        const int g = rr / 48, jj = rr - g * 48;
        const int c = (sb & 7) ^ (rr & 7);
        srcs[4] = whh16 + (size_t)g * HP * HP + (size_t)(gn0 + jj) * HP + c * 8;
    }

    f32x4 acc[4][3];
#pragma unroll
    for (int m = 0; m < 4; ++m)
#pragma unroll
        for (int n = 0; n < 3; ++n) acc[m][n] = (f32x4){0.f, 0.f, 0.f, 0.f};

    // stage: waves 0,1 issue 5 load-instrs/tile, waves 2..11 issue 4.
    auto STAGE = [&](int kt, char* bufc) {
        const int ko = kt * 64;
#pragma unroll
        for (int i = 0; i < 4; ++i)
            gload16(srcs[i] + ko, bufc + (i * 12 + wid) * 1024);
        if (tid < 128) gload16(srcs[4] + ko, bufc + (48 + wid) * 1024);
    };

    STAGE(0, smem);
    STAGE(1, smem + BUFSZ);

    int cur = 0;
    for (int t = 0; t < KT; ++t) {
        // counted vmcnt BEFORE barrier: own tile-t loads certified, t+1's stay in flight.
        if (t == KT - 1)      asm volatile("s_waitcnt vmcnt(0)" ::: "memory");
        else if (wid < 2)     asm volatile("s_waitcnt vmcnt(5)" ::: "memory");
        else                  asm volatile("s_waitcnt vmcnt(4)" ::: "memory");
        __builtin_amdgcn_s_barrier();
        __builtin_amdgcn_sched_barrier(0);           // pin: no ds_read above the barrier

        const char* bufc = smem + cur * BUFSZ;
        // ---- hoisted fragment reads: BOTH kk halves up front (14 ds_read_b128)
        f16x8 af[2][4], bf[2][3];
#pragma unroll
        for (int kk = 0; kk < 2; ++kk) {
            const int ko = (kk * 64 + lhi * 16) ^ swz;
#pragma unroll
            for (int m = 0; m < 4; ++m)
                af[kk][m] = *reinterpret_cast<const f16x8*>(bufc + (wm * 64 + m * 16 + l15) * 128 + ko);
#pragma unroll
            for (int n = 0; n < 3; ++n)
                bf[kk][n] = *reinterpret_cast<const f16x8*>(bufc + 32768 + (wn * 48 + n * 16 + l15) * 128 + ko);
        }
        // ---- issue next-next tile staging while reads are in flight
        if (t + 2 < KT) {
            int b2 = cur + 2; if (b2 >= 3) b2 -= 3;
            STAGE(t + 2, smem + b2 * BUFSZ);
        }
        // ---- single 24-MFMA cluster (compiler inserts fine-grained lgkmcnt)
        __builtin_amdgcn_s_setprio(1);
#pragma unroll
        for (int kk = 0; kk < 2; ++kk)
#pragma unroll
            for (int m = 0; m < 4; ++m)
#pragma unroll
                for (int n = 0; n < 3; ++n)
                    acc[m][n] = __builtin_amdgcn_mfma_f32_16x16x32_f16(af[kk][m], bf[kk][n], acc[m][n], 0, 0, 0);
        __builtin_amdgcn_s_setprio(0);

        ++cur; if (cur == 3) cur = 0;
    }

    // ---- epilogue: exchange gates via LDS planes, then all threads do gate math
    __syncthreads();
    float* planes = reinterpret_cast<float*>(smem);
    {
        float* myplane = planes + wn * PLANE;
#pragma unroll
        for (int m = 0; m < 4; ++m)
#pragma unroll
            for (int n = 0; n < 3; ++n)
#pragma unroll
                for (int e = 0; e < 4; ++e)
                    myplane[(wm * 64 + m * 16 + lhi * 4 + e) * 52 + n * 16 + l15] = acc[m][n][e];
    }
    __syncthreads();

#pragma unroll
    for (int cc = 0; cc < 2; ++cc) {
        const int c = tid + cc * 768;                 // 1536 chunks of 8
        const int row = c / 6;
        const int coff = (c - row * 6) * 8;
        const int b = gm0 + row;
        const int jb = gn0 + coff;
        if (jb >= HID) continue;
        const float x0 = xprev[b * 4 + 0], x1 = xprev[b * 4 + 1], x2 = xprev[b * 4 + 2];
        const int pb = row * 52 + coff;
        const int nv = (jb + 8 <= HID) ? 8 : (HID - jb);
        float hn[8];
        if (nv == 8) {
            const f16x8 hp8 = *reinterpret_cast<const f16x8*>(h16c + (size_t)b * HP + jb);
#pragma unroll
            for (int i = 0; i < 8; ++i) {
                const int j = jb + i;
                const float g0 = planes[pb + i];
                const float g1 = planes[PLANE + pb + i];
                const float g2 = planes[2 * PLANE + pb + i];
                const float4* p4 = reinterpret_cast<const float4*>(pk + (size_t)j * 16);
                const float4 q0 = p4[0];   // w00 w01 w02 w10
                const float4 q1 = p4[1];   // w11 w12 w20 w21
                const float4 q2 = p4[2];   // w22 bi0 bi1 bi2
                const float4 q3 = p4[3];   // bh2 - - -
                const float r = sigf(x0 * q0.x + x1 * q0.y + x2 * q0.z + q2.y + g0);
                const float u = sigf(x0 * q0.w + x1 * q1.x + x2 * q1.y + q2.z + g1);
                const float nn = tanhf_(x0 * q1.z + x1 * q1.w + x2 * q2.x + q2.w
                                        + r * (g2 + q3.x));
                hn[i] = (1.f - u) * nn + u * (float)hp8[i];
            }
            f16x8 hv;
#pragma unroll
            for (int i = 0; i < 8; ++i) hv[i] = (f16)hn[i];
            *reinterpret_cast<f16x8*>(h16n + (size_t)b * HP + jb) = hv;
        } else {
            for (int i = 0; i < nv; ++i) {
                const int j = jb + i;
                const float g0 = planes[pb + i];
                const float g1 = planes[PLANE + pb + i];
                const float g2 = planes[2 * PLANE + pb + i];
                const float4* p4 = reinterpret_cast<const float4*>(pk + (size_t)j * 16);
                const float4 q0 = p4[0];
                const float4 q1 = p4[1];
                const float4 q2 = p4[2];
                const float4 q3 = p4[3];
                const float r = sigf(x0 * q0.x + x1 * q0.y + x2 * q0.z + q2.y + g0);
                const float u = sigf(x0 * q0.w + x1 * q1.x + x2 * q1.y + q2.z + g1);
                const float nn = tanhf_(x0 * q1.z + x1 * q1.w + x2 * q2.x + q2.w
                                        + r * (g2 + q3.x));
                const float hp_ = (float)h16c[(size_t)b * HP + j];
                h16n[(size_t)b * HP + j] = (f16)((1.f - u) * nn + u * hp_);
            }
        }
    }
}

// ---------------- waypoint readout: wave-per-row (4 rows/block), fp32 Wo
__global__ __launch_bounds__(256) void x_update(const f16* __restrict__ hn,
                                                const float* __restrict__ Wo,
                                                const float* __restrict__ bo,
                                                const float* __restrict__ xp,
                                                float* __restrict__ xn,
                                                float* __restrict__ out, int s)
{
    const int w = threadIdx.x >> 6, lane = threadIdx.x & 63;
    const int b = blockIdx.x * 4 + w;
    float a0 = 0.f, a1 = 0.f, a2 = 0.f;
#pragma unroll
    for (int i = 0; i < 6; ++i) {
        const int ch = i * 64 + lane;
        if (ch < 375) {                               // 375*8 = 3000 exactly
            const int k = ch * 8;
            f16x8 h8 = *reinterpret_cast<const f16x8*>(hn + (size_t)b * HP + k);
#pragma unroll
            for (int q = 0; q < 8; ++q) {
                const float hv = (float)h8[q];
                a0 += hv * Wo[k + q];
                a1 += hv * Wo[HID + k + q];
                a2 += hv * Wo[2 * HID + k + q];
            }
        }
    }
#pragma unroll
    for (int off = 32; off; off >>= 1) {
        a0 += __shfl_down(a0, off);
        a1 += __shfl_down(a1, off);
        a2 += __shfl_down(a2, off);
    }
    if (lane == 0) {
        const float r0 = a0 + bo[0] + xp[b * 4 + 0];
        const float r1 = a1 + bo[1] + xp[b * 4 + 1];
        const float r2 = a2 + bo[2] + xp[b * 4 + 2];
        xn[b * 4 + 0] = r0; xn[b * 4 + 1] = r1; xn[b * 4 + 2] = r2;
        float* o = out + ((size_t)b * 30 + s) * 3;
        o[0] = r0; o[1] = r1; o[2] = r2;
    }
}

extern "C" void kernel_launch(void* const* d_in, const int* in_sizes, int n_in,
                              void* d_out, int out_size, void* d_ws, size_t ws_size,
                              hipStream_t stream)
{
    (void)in_sizes; (void)n_in; (void)out_size; (void)ws_size;
    const float* z   = (const float*)d_in[0];
    const float* W1  = (const float*)d_in[1];
    const float* b1  = (const float*)d_in[2];
    const float* W2  = (const float*)d_in[3];
    const float* b2  = (const float*)d_in[4];
    const float* W3  = (const float*)d_in[5];
    const float* b3  = (const float*)d_in[6];
    const float* Wih = (const float*)d_in[7];
    const float* bih = (const float*)d_in[8];
    const float* Whh = (const float*)d_in[9];
    const float* bhh = (const float*)d_in[10];
    const float* Wo  = (const float*)d_in[11];
    const float* bo  = (const float*)d_in[12];
    float* out = (float*)d_out;

    char* ws = (char*)d_ws;
    size_t off = 0;
    f16* whh16 = (f16*)(ws + off); off += (size_t)3 * HP * HP * 2;
    f16* h16[2];
    h16[0] = (f16*)(ws + off); off += (size_t)NB * HP * 2;
    h16[1] = (f16*)(ws + off); off += (size_t)NB * HP * 2;
    float* h1  = (float*)(ws + off); off += (size_t)NB * 512 * 4;
    float* h2  = (float*)(ws + off); off += (size_t)NB * 256 * 4;
    f16*   h2h = (f16*)(ws + off);   off += (size_t)NB * 256 * 2;
    f16*   w3f16 = (f16*)(ws + off); off += (size_t)HP * 256 * 2;
    float* pk  = (float*)(ws + off); off += (size_t)HID * 16 * 4;
    float* xb  = (float*)(ws + off); off += (size_t)31 * NB * 4 * 4;

    // zero both f16 h buffers (pad columns must stay 0 as MFMA K inputs) and x_0
    hipMemsetAsync(h16[0], 0, (size_t)2 * NB * HP * 2, stream);
    hipMemsetAsync(xb, 0, (size_t)NB * 4 * 4, stream);

    {
        int s32 = 3 * HP * (HP / 32);
        convert_whh<<<(s32 + 255) / 256, 256, 0, stream>>>(Whh, whh16);
    }
    convert_w3<<<(HP * 32 + 255) / 256, 256, 0, stream>>>(W3, w3f16);
    pack_gates<<<(HID + 255) / 256, 256, 0, stream>>>(Wih, bih, bhh, pk);

    mlp_layer<<<NB / 4, 256, 0, stream>>>(z,  256, 512, 512, W1, b1, h1, nullptr);
    mlp_layer<<<NB / 4, 256, 0, stream>>>(h1, 512, 256, 256, W2, b2, h2, h2h);
    mlp3_mfma<<<dim3(HP / BN, NB / BM), 256, 0, stream>>>(h2h, w3f16, b3, h16[0]);

    for (int s = 1; s <= 30; ++s) {
        int cur = (s - 1) & 1, nxt = s & 1;
        gru_step<<<256, 768, 0, stream>>>(
            h16[cur], whh16, xb + (size_t)(s - 1) * NB * 4,
            pk, h16[nxt]);
        x_update<<<NB / 4, 256, 0, stream>>>(h16[nxt], Wo, bo,
            xb + (size_t)(s - 1) * NB * 4, xb + (size_t)s * NB * 4, out, s - 1);
    }
}

// Round 14
// 2139.729 us; speedup vs baseline: 1.1169x; 1.1169x over previous
//
#include <hip/hip_runtime.h>
#include <cstdint>
#include <cstddef>

#define HID 3000
#define HP  3072          // padded hidden (2^10 * 3)
#define NB  1024          // batch
#define BM  128           // mlp3 tile
#define BN  64            // mlp3 per-tile N
#define KT  48            // HP/64 K-steps for gru
#define BUFSZ 51200       // gru LDS buffer: A 256x64 f16 (32KB) + B 144x64 f16 (18KB)
#define PLANE 13312       // 256*52 f32 per gate plane (epilogue)

typedef _Float16 f16;
typedef _Float16 f16x8 __attribute__((ext_vector_type(8)));
typedef float    f32x4 __attribute__((ext_vector_type(4)));

__device__ __forceinline__ float sigf(float v)  { return 1.0f / (1.0f + __expf(-v)); }
__device__ __forceinline__ float tanhf_(float v){ return 2.0f / (1.0f + __expf(-2.0f * v)) - 1.0f; }

// async global->LDS, 16B per lane. LDS dest = wave-uniform base + lane*16 (linear).
__device__ __forceinline__ void gload16(const void* g, void* l) {
    __builtin_amdgcn_global_load_lds((const __attribute__((address_space(1))) void*)g,
                                     (__attribute__((address_space(3))) void*)l, 16, 0, 0);
}

// ---------------- Whh fp32 -> fp16, padded [3][HP][HP]; 128B-in/64B-out per thread
__global__ __launch_bounds__(256) void convert_whh(const float* __restrict__ whh,
                                                   f16* __restrict__ whh16)
{
    const int S32 = 3 * HP * (HP / 32);
    int t = blockIdx.x * 256 + threadIdx.x;
    if (t >= S32) return;
    const int c32 = (t % (HP / 32)) * 32;
    const int rr  = (t / (HP / 32)) % HP;
    const int g   = t / ((HP / 32) * HP);
    f16* dst = whh16 + ((size_t)g * HP + rr) * HP + c32;
    if (rr < HID && c32 + 32 <= HID) {
        const float* src = whh + (size_t)(g * HID + rr) * HID + c32;
#pragma unroll
        for (int u = 0; u < 4; ++u) {
            float4 lo = *reinterpret_cast<const float4*>(src + u * 8);
            float4 hi = *reinterpret_cast<const float4*>(src + u * 8 + 4);
            f16x8 v;
            v[0] = (f16)lo.x; v[1] = (f16)lo.y; v[2] = (f16)lo.z; v[3] = (f16)lo.w;
            v[4] = (f16)hi.x; v[5] = (f16)hi.y; v[6] = (f16)hi.z; v[7] = (f16)hi.w;
            *reinterpret_cast<f16x8*>(dst + u * 8) = v;
        }
    } else {
#pragma unroll
        for (int u = 0; u < 4; ++u) {
            f16x8 v;
#pragma unroll
            for (int k = 0; k < 8; ++k) {
                const int cc = c32 + u * 8 + k;
                v[k] = (rr < HID && cc < HID) ? (f16)whh[(size_t)(g * HID + rr) * HID + cc]
                                              : (f16)0.0f;
            }
            *reinterpret_cast<f16x8*>(dst + u * 8) = v;
        }
    }
}

// ---------------- W3 fp32 [3000][256] -> f16 [HP][256], zero-padded rows
__global__ __launch_bounds__(256) void convert_w3(const float* __restrict__ w,
                                                  f16* __restrict__ w16)
{
    int t = blockIdx.x * 256 + threadIdx.x;      // HP * 32 slots of 8
    if (t >= HP * 32) return;
    int rr = t >> 5, c8 = (t & 31) * 8;
    f16x8 v;
    if (rr < HID) {
        const float* src = w + (size_t)rr * 256 + c8;
        float4 lo = *reinterpret_cast<const float4*>(src);
        float4 hi = *reinterpret_cast<const float4*>(src + 4);
        v[0] = (f16)lo.x; v[1] = (f16)lo.y; v[2] = (f16)lo.z; v[3] = (f16)lo.w;
        v[4] = (f16)hi.x; v[5] = (f16)hi.y; v[6] = (f16)hi.z; v[7] = (f16)hi.w;
    } else {
#pragma unroll
        for (int i = 0; i < 8; ++i) v[i] = (f16)0.0f;
    }
    *reinterpret_cast<f16x8*>(w16 + (size_t)rr * 256 + c8) = v;
}

// ---------------- small fp32 MLP layer: out = relu(A @ W^T + b), optional f16 copy
__global__ __launch_bounds__(256) void mlp_layer(const float* __restrict__ A, int K, int N, int ldo,
                                                 const float* __restrict__ W,
                                                 const float* __restrict__ bias,
                                                 float* __restrict__ outf, f16* __restrict__ outh)
{
    __shared__ float sA[4 * 512];
    const int b0 = blockIdx.x * 4;
    for (int idx = threadIdx.x; idx < 4 * K; idx += 256)
        sA[idx] = A[(size_t)b0 * K + idx];
    __syncthreads();
    for (int n = threadIdx.x; n < ldo; n += 256) {
        float acc[4] = {0.f, 0.f, 0.f, 0.f};
        if (n < N) {
            const float4* wr = reinterpret_cast<const float4*>(W + (size_t)n * K);
            for (int kk = 0; kk < (K >> 2); ++kk) {
                float4 w = wr[kk];
#pragma unroll
                for (int r = 0; r < 4; ++r) {
                    const float* ar = sA + r * K + kk * 4;
                    acc[r] += ar[0] * w.x + ar[1] * w.y + ar[2] * w.z + ar[3] * w.w;
                }
            }
            float bv = bias[n];
#pragma unroll
            for (int r = 0; r < 4; ++r) acc[r] = fmaxf(acc[r] + bv, 0.f);
        }
#pragma unroll
        for (int r = 0; r < 4; ++r) {
            outf[(size_t)(b0 + r) * ldo + n] = acc[r];
            if (outh) outh[(size_t)(b0 + r) * ldo + n] = (f16)acc[r];
        }
    }
}

// ---------------- W3 layer via MFMA: out = relu(A @ B^T + b3); A [NB][256] f16, B [HP][256] f16
__global__ __launch_bounds__(256, 2)
void mlp3_mfma(const f16* __restrict__ A, const f16* __restrict__ B,
               const float* __restrict__ bias,
               float* __restrict__ outf, f16* __restrict__ outh)
{
    __shared__ __align__(16) char smem[24576];   // sA 16KB | sB 8KB
    char* sBm = smem + 16384;

    const int tid  = threadIdx.x;
    const int lane = tid & 63;
    const int wid  = tid >> 6;
    const int wm = wid >> 1, wn = wid & 1;
    const int l15 = lane & 15, lhi = lane >> 4;
    const int swz = (lane & 7) << 4;

    const int gm0 = blockIdx.y * BM, gn0 = blockIdx.x * BN;

    const f16* a_srcs[4]; char* a_ldst[4];
#pragma unroll
    for (int i = 0; i < 4; ++i) {
        const int d = (i * 4 + wid) * 64 + lane;          // [0,1024)
        const int r = d >> 3;
        const int c = (d & 7) ^ (r & 7);
        a_srcs[i] = A + (size_t)(gm0 + r) * 256 + c * 8;
        a_ldst[i] = smem + (i * 4 + wid) * 1024;
    }
    const f16* b_srcs[2]; char* b_ldst[2];
#pragma unroll
    for (int i = 0; i < 2; ++i) {
        const int d = (i * 4 + wid) * 64 + lane;          // [0,512)
        const int rr = d >> 3;
        const int c = (d & 7) ^ (rr & 7);
        b_srcs[i] = B + (size_t)(gn0 + rr) * 256 + c * 8;
        b_ldst[i] = sBm + (i * 4 + wid) * 1024;
    }

    f32x4 acc[4][2];
#pragma unroll
    for (int m = 0; m < 4; ++m)
#pragma unroll
        for (int n = 0; n < 2; ++n) acc[m][n] = (f32x4){0.f, 0.f, 0.f, 0.f};

    for (int kt = 0; kt < 4; ++kt) {
        const int kg = kt * 64;
#pragma unroll
        for (int i = 0; i < 4; ++i) gload16(a_srcs[i] + kg, a_ldst[i]);
#pragma unroll
        for (int i = 0; i < 2; ++i) gload16(b_srcs[i] + kg, b_ldst[i]);
        __syncthreads();
#pragma unroll
        for (int kk = 0; kk < 2; ++kk) {
            const int ko = (kk * 64 + lhi * 16) ^ swz;
            f16x8 af[4], bf[2];
#pragma unroll
            for (int m = 0; m < 4; ++m)
                af[m] = *reinterpret_cast<const f16x8*>(smem + (wm * 64 + m * 16 + l15) * 128 + ko);
#pragma unroll
            for (int n = 0; n < 2; ++n)
                bf[n] = *reinterpret_cast<const f16x8*>(sBm + (wn * 32 + n * 16 + l15) * 128 + ko);
#pragma unroll
            for (int m = 0; m < 4; ++m)
#pragma unroll
                for (int n = 0; n < 2; ++n)
                    acc[m][n] = __builtin_amdgcn_mfma_f32_16x16x32_f16(af[m], bf[n], acc[m][n], 0, 0, 0);
        }
        __syncthreads();
    }

#pragma unroll
    for (int m = 0; m < 4; ++m) {
#pragma unroll
        for (int e = 0; e < 4; ++e) {
            const int b = gm0 + wm * 64 + m * 16 + lhi * 4 + e;
#pragma unroll
            for (int n = 0; n < 2; ++n) {
                const int j = gn0 + wn * 32 + n * 16 + l15;
                if (j < HID) {
                    float v = fmaxf(acc[m][n][e] + bias[j], 0.f);
                    outf[(size_t)b * HP + j] = v;
                    outh[(size_t)b * HP + j] = (f16)v;
                }
            }
        }
    }
}

// ---------------- fused GRU step (R5 skeleton + hoisted-read single-cluster K-step):
// 256x144 tile, 12 waves (4M x 3N=gate), grid 256 = 1/CU. Triple-buffered LDS, depth-2
// prefetch, ONE barrier + counted vmcnt per K-step. Per interval: 14 ds_read (both kk
// halves) -> STAGE issue -> 24-MFMA setprio cluster. LDS-plane gate exchange epilogue.
__global__ __launch_bounds__(768, 3)
void gru_step(const f16* __restrict__ h16c, float* __restrict__ hf32,
              const f16* __restrict__ whh16,
              const float* __restrict__ xprev,
              const float* __restrict__ Wih, const float* __restrict__ bih,
              const float* __restrict__ bhh,
              f16* __restrict__ h16n)
{
    __shared__ __align__(16) char smem[159744];  // 3 x 51200 bufs; reused as 3 x 53248 planes

    const int tid  = threadIdx.x;
    const int lane = tid & 63;
    const int wid  = tid >> 6;          // 0..11
    const int wm   = wid & 3;           // row group: rows [wm*64, wm*64+64)
    const int wn   = wid >> 2;          // gate 0..2
    const int l15 = lane & 15, lhi = lane >> 4;
    const int swz = (lane & 7) << 4;

    // XCD-bijective: xcd owns bn in [8*xcd, 8*xcd+8); the 4 bm-blocks of a bn share one XCD.
    const int id = blockIdx.x;
    const int xcd = id & 7, local = id >> 3;
    const int bn = xcd * 8 + (local >> 2), bm = local & 3;
    const int gm0 = bm * 256, gn0 = bn * 48;

    // staging: slots of 16B. A: 0..2047 (256 rows x 8), B: 2048..3199 (144 rows x 8).
    // LDS dest linear (slot*16); inverse XOR-swizzle applied to the GLOBAL source column.
    const f16* srcs[5];
#pragma unroll
    for (int i = 0; i < 4; ++i) {
        const int s = i * 768 + tid;
        if (s < 2048) {
            const int r = s >> 3;
            const int c = (s & 7) ^ (r & 7);
            srcs[i] = h16c + (size_t)(gm0 + r) * HP + c * 8;
        } else {
            const int sb = s - 2048;
            const int rr = sb >> 3;                  // g*48 + j'
            const int g = rr / 48, jj = rr - g * 48;
            const int c = (sb & 7) ^ (rr & 7);
            srcs[i] = whh16 + (size_t)g * HP * HP + (size_t)(gn0 + jj) * HP + c * 8;
        }
    }
    {
        const int sb = 1024 + tid;                   // used only when tid < 128
        const int rr = sb >> 3;                      // 128..143 -> gate 2
        const int g = rr / 48, jj = rr - g * 48;
        const int c = (sb & 7) ^ (rr & 7);
        srcs[4] = whh16 + (size_t)g * HP * HP + (size_t)(gn0 + jj) * HP + c * 8;
    }

    f32x4 acc[4][3];
#pragma unroll
    for (int m = 0; m < 4; ++m)
#pragma unroll
        for (int n = 0; n < 3; ++n) acc[m][n] = (f32x4){0.f, 0.f, 0.f, 0.f};

    // stage: waves 0,1 issue 5 load-instrs/tile, waves 2..11 issue 4.
    auto STAGE = [&](int kt, char* bufc) {
        const int ko = kt * 64;
#pragma unroll
        for (int i = 0; i < 4; ++i)
            gload16(srcs[i] + ko, bufc + (i * 12 + wid) * 1024);
        if (tid < 128) gload16(srcs[4] + ko, bufc + (48 + wid) * 1024);
    };

    STAGE(0, smem);
    STAGE(1, smem + BUFSZ);

    int cur = 0;
    for (int t = 0; t < KT; ++t) {
        // counted vmcnt BEFORE barrier: own tile-t loads certified, t+1's stay in flight.
        if (t == KT - 1)      asm volatile("s_waitcnt vmcnt(0)" ::: "memory");
        else if (wid < 2)     asm volatile("s_waitcnt vmcnt(5)" ::: "memory");
        else                  asm volatile("s_waitcnt vmcnt(4)" ::: "memory");
        __builtin_amdgcn_s_barrier();
        __builtin_amdgcn_sched_barrier(0);           // pin: no ds_read above the barrier

        const char* bufc = smem + cur * BUFSZ;
        // ---- hoisted fragment reads: BOTH kk halves up front (14 ds_read_b128)
        f16x8 af[2][4], bf[2][3];
#pragma unroll
        for (int kk = 0; kk < 2; ++kk) {
            const int ko = (kk * 64 + lhi * 16) ^ swz;
#pragma unroll
            for (int m = 0; m < 4; ++m)
                af[kk][m] = *reinterpret_cast<const f16x8*>(bufc + (wm * 64 + m * 16 + l15) * 128 + ko);
#pragma unroll
            for (int n = 0; n < 3; ++n)
                bf[kk][n] = *reinterpret_cast<const f16x8*>(bufc + 32768 + (wn * 48 + n * 16 + l15) * 128 + ko);
        }
        // ---- issue next-next tile staging while reads are in flight
        if (t + 2 < KT) {
            int b2 = cur + 2; if (b2 >= 3) b2 -= 3;
            STAGE(t + 2, smem + b2 * BUFSZ);
        }
        // ---- single 24-MFMA cluster (compiler inserts fine-grained lgkmcnt)
        __builtin_amdgcn_s_setprio(1);
#pragma unroll
        for (int kk = 0; kk < 2; ++kk)
#pragma unroll
            for (int m = 0; m < 4; ++m)
#pragma unroll
                for (int n = 0; n < 3; ++n)
                    acc[m][n] = __builtin_amdgcn_mfma_f32_16x16x32_f16(af[kk][m], bf[kk][n], acc[m][n], 0, 0, 0);
        __builtin_amdgcn_s_setprio(0);

        ++cur; if (cur == 3) cur = 0;
    }

    // ---- epilogue: exchange gates via LDS planes, then all threads do gate math
    __syncthreads();
    float* planes = reinterpret_cast<float*>(smem);
    {
        float* myplane = planes + wn * PLANE;
#pragma unroll
        for (int m = 0; m < 4; ++m)
#pragma unroll
            for (int n = 0; n < 3; ++n)
#pragma unroll
                for (int e = 0; e < 4; ++e)
                    myplane[(wm * 64 + m * 16 + lhi * 4 + e) * 52 + n * 16 + l15] = acc[m][n][e];
    }
    __syncthreads();

#pragma unroll
    for (int cc = 0; cc < 2; ++cc) {
        const int c = tid + cc * 768;                 // 1536 chunks of 8
        const int row = c / 6;
        const int coff = (c - row * 6) * 8;
        const int b = gm0 + row;
        const int jb = gn0 + coff;
        if (jb >= HID) continue;
        const float x0 = xprev[b * 4 + 0], x1 = xprev[b * 4 + 1], x2 = xprev[b * 4 + 2];
        const int pb = row * 52 + coff;
        const int nv = (jb + 8 <= HID) ? 8 : (HID - jb);
        float hn[8];
#pragma unroll
        for (int i = 0; i < 8; ++i) {
            if (i < nv) {
                const int j = jb + i;
                const float g0 = planes[pb + i];
                const float g1 = planes[PLANE + pb + i];
                const float g2 = planes[2 * PLANE + pb + i];
                const float* w0 = Wih + (size_t)j * 3;
                const float* w1 = Wih + (size_t)(HID + j) * 3;
                const float* w2 = Wih + (size_t)(2 * HID + j) * 3;
                const float gi0 = x0 * w0[0] + x1 * w0[1] + x2 * w0[2] + bih[j];
                const float gi1 = x0 * w1[0] + x1 * w1[1] + x2 * w1[2] + bih[HID + j];
                const float gi2 = x0 * w2[0] + x1 * w2[1] + x2 * w2[2] + bih[2 * HID + j];
                const float r = sigf(gi0 + g0 + bhh[j]);
                const float u = sigf(gi1 + g1 + bhh[HID + j]);
                const float nn = tanhf_(gi2 + r * (g2 + bhh[2 * HID + j]));
                const float hp_ = hf32[(size_t)b * HP + j];
                hn[i] = (1.f - u) * nn + u * hp_;
            }
        }
        if (nv == 8) {
            f16x8 hv;
#pragma unroll
            for (int i = 0; i < 8; ++i) hv[i] = (f16)hn[i];
            *reinterpret_cast<f16x8*>(h16n + (size_t)b * HP + jb) = hv;
            float4 f0 = {hn[0], hn[1], hn[2], hn[3]};
            float4 f1 = {hn[4], hn[5], hn[6], hn[7]};
            *reinterpret_cast<float4*>(hf32 + (size_t)b * HP + jb) = f0;
            *reinterpret_cast<float4*>(hf32 + (size_t)b * HP + jb + 4) = f1;
        } else {
            for (int i = 0; i < nv; ++i) {
                hf32[(size_t)b * HP + jb + i] = hn[i];
                h16n[(size_t)b * HP + jb + i] = (f16)hn[i];
            }
        }
    }
}

// ---------------- waypoint readout: wave-per-row (4 rows/block), fp32 Wo
__global__ __launch_bounds__(256) void x_update(const f16* __restrict__ hn,
                                                const float* __restrict__ Wo,
                                                const float* __restrict__ bo,
                                                const float* __restrict__ xp,
                                                float* __restrict__ xn,
                                                float* __restrict__ out, int s)
{
    const int w = threadIdx.x >> 6, lane = threadIdx.x & 63;
    const int b = blockIdx.x * 4 + w;
    float a0 = 0.f, a1 = 0.f, a2 = 0.f;
#pragma unroll
    for (int i = 0; i < 6; ++i) {
        const int ch = i * 64 + lane;
        if (ch < 375) {                               // 375*8 = 3000 exactly
            const int k = ch * 8;
            f16x8 h8 = *reinterpret_cast<const f16x8*>(hn + (size_t)b * HP + k);
#pragma unroll
            for (int q = 0; q < 8; ++q) {
                const float hv = (float)h8[q];
                a0 += hv * Wo[k + q];
                a1 += hv * Wo[HID + k + q];
                a2 += hv * Wo[2 * HID + k + q];
            }
        }
    }
#pragma unroll
    for (int off = 32; off; off >>= 1) {
        a0 += __shfl_down(a0, off);
        a1 += __shfl_down(a1, off);
        a2 += __shfl_down(a2, off);
    }
    if (lane == 0) {
        const float r0 = a0 + bo[0] + xp[b * 4 + 0];
        const float r1 = a1 + bo[1] + xp[b * 4 + 1];
        const float r2 = a2 + bo[2] + xp[b * 4 + 2];
        xn[b * 4 + 0] = r0; xn[b * 4 + 1] = r1; xn[b * 4 + 2] = r2;
        float* o = out + ((size_t)b * 30 + s) * 3;
        o[0] = r0; o[1] = r1; o[2] = r2;
    }
}

extern "C" void kernel_launch(void* const* d_in, const int* in_sizes, int n_in,
                              void* d_out, int out_size, void* d_ws, size_t ws_size,
                              hipStream_t stream)
{
    (void)in_sizes; (void)n_in; (void)out_size; (void)ws_size;
    const float* z   = (const float*)d_in[0];
    const float* W1  = (const float*)d_in[1];
    const float* b1  = (const float*)d_in[2];
    const float* W2  = (const float*)d_in[3];
    const float* b2  = (const float*)d_in[4];
    const float* W3  = (const float*)d_in[5];
    const float* b3  = (const float*)d_in[6];
    const float* Wih = (const float*)d_in[7];
    const float* bih = (const float*)d_in[8];
    const float* Whh = (const float*)d_in[9];
    const float* bhh = (const float*)d_in[10];
    const float* Wo  = (const float*)d_in[11];
    const float* bo  = (const float*)d_in[12];
    float* out = (float*)d_out;

    char* ws = (char*)d_ws;
    size_t off = 0;
    f16* whh16 = (f16*)(ws + off); off += (size_t)3 * HP * HP * 2;
    f16* h16[2];
    h16[0] = (f16*)(ws + off); off += (size_t)NB * HP * 2;
    h16[1] = (f16*)(ws + off); off += (size_t)NB * HP * 2;
    float* hf  = (float*)(ws + off); off += (size_t)NB * HP * 4;   // in-place fp32 state
    float* h1  = (float*)(ws + off); off += (size_t)NB * 512 * 4;
    float* h2  = (float*)(ws + off); off += (size_t)NB * 256 * 4;
    f16*   h2h = (f16*)(ws + off);   off += (size_t)NB * 256 * 2;
    f16*   w3f16 = (f16*)(ws + off); off += (size_t)HP * 256 * 2;
    float* xb  = (float*)(ws + off); off += (size_t)31 * NB * 4 * 4;

    // zero both f16 h buffers (pad columns must stay 0 as MFMA K inputs) and x_0
    hipMemsetAsync(h16[0], 0, (size_t)2 * NB * HP * 2, stream);
    hipMemsetAsync(xb, 0, (size_t)NB * 4 * 4, stream);

    {
        int s32 = 3 * HP * (HP / 32);
        convert_whh<<<(s32 + 255) / 256, 256, 0, stream>>>(Whh, whh16);
    }
    convert_w3<<<(HP * 32 + 255) / 256, 256, 0, stream>>>(W3, w3f16);

    mlp_layer<<<NB / 4, 256, 0, stream>>>(z,  256, 512, 512, W1, b1, h1, nullptr);
    mlp_layer<<<NB / 4, 256, 0, stream>>>(h1, 512, 256, 256, W2, b2, h2, h2h);
    mlp3_mfma<<<dim3(HP / BN, NB / BM), 256, 0, stream>>>(h2h, w3f16, b3, hf, h16[0]);

    for (int s = 1; s <= 30; ++s) {
        int cur = (s - 1) & 1, nxt = s & 1;
        gru_step<<<256, 768, 0, stream>>>(
            h16[cur], hf, whh16, xb + (size_t)(s - 1) * NB * 4,
            Wih, bih, bhh, h16[nxt]);
        x_update<<<NB / 4, 256, 0, stream>>>(h16[nxt], Wo, bo,
            xb + (size_t)(s - 1) * NB * 4, xb + (size_t)s * NB * 4, out, s - 1);
    }
}